// Round 6
// baseline (227.918 us; speedup 1.0000x reference)
//
#include <hip/hip_runtime.h>
#include <hip/hip_bf16.h>
#include <math.h>

#define NN 50000
#define NE 500000
#define IC 128
#define OC 256
#define NPAD 50176            // 196 * 256
#define NB 196                // scan blocks
#define NEB4 489              // ceil(NE/1024) edge blocks, 4 edges/thread
#define CONVSTRIDE (NEB4 * 256)

typedef short bf16x8 __attribute__((ext_vector_type(8)));
typedef float f32x4 __attribute__((ext_vector_type(4)));

static __device__ inline unsigned short f2b(float f) {
    __hip_bfloat16 h = __float2bfloat16(f);   // RNE
    return *reinterpret_cast<unsigned short*>(&h);
}
static __device__ inline float b2f(short u) {
    unsigned v = ((unsigned)(unsigned short)u) << 16;
    return __int_as_float(v);
}

// ---------------- init: deg64 = (count=0, degfix = 1.0 in 8.24) ----------------
__global__ void k_init(unsigned long long* __restrict__ deg64) {
    int i = blockIdx.x * 256 + threadIdx.x;   // i < NPAD
    deg64[i] = (unsigned long long)(1u << 24);   // self-loop weight 1
}

// ---------------- pass1: 4 edges/thread, 4 independent u64 atomics in flight;
//                  fused x->bf16 and W->WT conversions ----------------
__global__ __launch_bounds__(256) void k_pass1(const int* __restrict__ col,
                        const float* __restrict__ ew,
                        unsigned long long* __restrict__ deg64,
                        int* __restrict__ eord,
                        const float* __restrict__ x,
                        unsigned short* __restrict__ xb,
                        const float* __restrict__ W,
                        unsigned short* __restrict__ WT) {
    const int base = blockIdx.x * 1024 + threadIdx.x;
    int   cs[4];
    float ws[4];
    #pragma unroll
    for (int j = 0; j < 4; ++j) {
        int e = base + j * 256;
        if (e < NE) { cs[j] = col[e]; ws[j] = ew[e]; }
    }
    unsigned long long olds[4];
    #pragma unroll
    for (int j = 0; j < 4; ++j) {
        int e = base + j * 256;
        if (e < NE) {
            float w = 1.0f / (1.0f + expf(-ws[j]));
            unsigned long long pack = (1ull << 32) | (unsigned long long)(unsigned)(w * 16777216.0f);
            olds[j] = atomicAdd(&deg64[cs[j]], pack);
        }
    }
    #pragma unroll
    for (int j = 0; j < 4; ++j) {
        int e = base + j * 256;
        if (e < NE) eord[e] = (int)(olds[j] >> 32);
    }
    // fused x -> bf16 (grid-stride over float4 units)
    const int g = blockIdx.x * 256 + threadIdx.x;
    const int NX = NN * (IC / 4);
    for (int i = g; i < NX; i += CONVSTRIDE) {
        float4 v = ((const float4*)x)[i];
        ushort4 o;
        o.x = f2b(v.x); o.y = f2b(v.y); o.z = f2b(v.z); o.w = f2b(v.w);
        ((ushort4*)xb)[i] = o;
    }
    // fused W -> W^T bf16
    if (g < IC * OC) {
        int k = g >> 8;
        int n = g & 255;
        WT[n * IC + k] = f2b(W[g]);
    }
}

// ---------------- dinv + block-scan (fused, same grid) ----------------
__global__ void k_dinv_scan(const unsigned long long* __restrict__ deg64,
                            float* __restrict__ dinv,
                            int* __restrict__ sp,
                            int* __restrict__ bsum) {
    __shared__ int s[256];
    int t = threadIdx.x;
    int i = blockIdx.x * 256 + t;
    unsigned long long v = deg64[i];
    int cnt = (int)(v >> 32);
    float deg = (float)(unsigned)v * (1.0f / 16777216.0f);
    dinv[i] = rsqrtf(deg);                    // deg >= 1 always
    s[t] = cnt;
    __syncthreads();
    #pragma unroll
    for (int off = 1; off < 256; off <<= 1) {
        int add = (t >= off) ? s[t - off] : 0;
        __syncthreads();
        s[t] += add;
        __syncthreads();
    }
    sp[i] = s[t] - cnt;                       // exclusive within block
    if (t == 255) bsum[blockIdx.x] = s[255];
}

__global__ void k_scan2(int* __restrict__ bsum) {
    __shared__ int s[256];
    int t = threadIdx.x;
    int v = (t < NB) ? bsum[t] : 0;
    s[t] = v;
    __syncthreads();
    #pragma unroll
    for (int off = 1; off < 256; off <<= 1) {
        int add = (t >= off) ? s[t - off] : 0;
        __syncthreads();
        s[t] += add;
        __syncthreads();
    }
    if (t < NB) bsum[t] = s[t] - v;           // exclusive block offsets
}

// ---------------- fill: no atomic, 4 edges/thread ----------------
__global__ __launch_bounds__(256) void k_fill(const int* __restrict__ row,
                       const int* __restrict__ col,
                       const float* __restrict__ ew,
                       const float* __restrict__ dinv,
                       const int* __restrict__ sp,
                       const int* __restrict__ bsum,
                       const int* __restrict__ eord,
                       int2* __restrict__ epack) {
    const int base = blockIdx.x * 1024 + threadIdx.x;
    #pragma unroll
    for (int j = 0; j < 4; ++j) {
        int e = base + j * 256;
        if (e < NE) {
            int r = row[e], t = col[e];
            float w = 1.0f / (1.0f + expf(-ew[e]));
            float nrm = dinv[r] * w * dinv[t];
            int pos = sp[t] + bsum[t >> 8] + eord[e];
            int2 p;
            p.x = r;
            p.y = __float_as_int(nrm);
            epack[pos] = p;
        }
    }
}

// ---------------- fused gather + GEMM ----------------
// block = 256 threads = 4 waves; 64 nodes/block; out tile 64m x 256n
// phase 1: wave-cooperative gather (1 wave per node, 4 edge-slots x 16 ch-lanes) -> LDS
// phase 2: MFMA 16x16x32, A from LDS, WT from global (L2-hot)
__global__ __launch_bounds__(256) void k_gathergemm(const unsigned short* __restrict__ xb,
                                                    const int* __restrict__ sp,
                                                    const int* __restrict__ bsum,
                                                    const int2* __restrict__ epack,
                                                    const float* __restrict__ dinv,
                                                    const unsigned short* __restrict__ WT,
                                                    const float* __restrict__ bias,
                                                    float* __restrict__ out) {
    __shared__ unsigned short As[64][IC + 8];   // +8 bf16 pad: 2-way banks only
    __shared__ int   sstart[65];
    __shared__ float sdinv[64];

    const int tid = threadIdx.x;
    const int nb = blockIdx.x * 64;

    // stage per-node metadata coalesced
    if (tid < 65) {
        int n = nb + tid;                       // n <= 50048 < NPAD always valid
        sstart[tid] = sp[n] + bsum[n >> 8];
        if (tid < 64) sdinv[tid] = dinv[n];
    }
    __syncthreads();

    const int w = tid >> 6;
    const int lane = tid & 63;
    const int eg = lane >> 4;       // edge slot 0..3
    const int l16 = lane & 15;      // channel group (8 bf16)

    // phase 1: 16 rounds, wave w handles node local = r*4 + w
    for (int r = 0; r < 16; ++r) {
        int local = r * 4 + w;
        int n = nb + local;
        float acc[8] = {0.f, 0.f, 0.f, 0.f, 0.f, 0.f, 0.f, 0.f};
        if (n < NN) {                            // wave-uniform
            if (eg == 0) {                       // self term counted once
                float di = sdinv[local];
                float s2 = di * di;
                bf16x8 xs = *(const bf16x8*)(xb + (size_t)n * IC + l16 * 8);
                #pragma unroll
                for (int c = 0; c < 8; ++c) acc[c] = b2f(xs[c]) * s2;
            }
            int s = sstart[local], t = sstart[local + 1];
            for (int e = s + eg; e < t; e += 4) {
                int2 p = epack[e];
                bf16x8 v = *(const bf16x8*)(xb + (size_t)p.x * IC + l16 * 8);
                float wg = __int_as_float(p.y);
                #pragma unroll
                for (int c = 0; c < 8; ++c) acc[c] += b2f(v[c]) * wg;
            }
            // reduce across the 4 edge slots (lanes xor 16, 32)
            #pragma unroll
            for (int c = 0; c < 8; ++c) {
                acc[c] += __shfl_xor(acc[c], 16);
                acc[c] += __shfl_xor(acc[c], 32);
            }
        }
        if (eg == 0) {
            bf16x8 o;
            #pragma unroll
            for (int c = 0; c < 8; ++c) o[c] = (short)f2b(acc[c]);
            *(bf16x8*)&As[local][l16 * 8] = o;
        }
    }
    __syncthreads();

    // phase 2: wave w covers n in [w*64, w*64+64), m in [nb, nb+64)
    const int n0 = w * 64;
    const int lm = lane & 15;
    const int lk = (lane >> 4) * 8;

    f32x4 acc[4][4] = {};
    #pragma unroll
    for (int ks = 0; ks < 4; ++ks) {
        const int k0 = ks * 32 + lk;
        bf16x8 wf[4], af[4];
        #pragma unroll
        for (int j = 0; j < 4; ++j)
            wf[j] = *(const bf16x8*)(WT + (size_t)(n0 + j * 16 + lm) * IC + k0);
        #pragma unroll
        for (int i = 0; i < 4; ++i)
            af[i] = *(const bf16x8*)&As[i * 16 + lm][k0];
        #pragma unroll
        for (int i = 0; i < 4; ++i)
            #pragma unroll
            for (int j = 0; j < 4; ++j)
                acc[i][j] = __builtin_amdgcn_mfma_f32_16x16x32_bf16(wf[j], af[i], acc[i][j], 0, 0, 0);
    }

    // swapped D layout: col(lane&15) = m, row((lane>>4)*4+reg) = n -> float4 along n
    const int mcol = lane & 15;
    const int nb4 = (lane >> 4) * 4;
    #pragma unroll
    for (int i = 0; i < 4; ++i) {
        int m = nb + i * 16 + mcol;
        if (m < NN) {
            #pragma unroll
            for (int j = 0; j < 4; ++j) {
                int nn = n0 + j * 16 + nb4;
                float4 bv = *(const float4*)&bias[nn];
                float4 o;
                o.x = acc[i][j][0] + bv.x;
                o.y = acc[i][j][1] + bv.y;
                o.z = acc[i][j][2] + bv.z;
                o.w = acc[i][j][3] + bv.w;
                *(float4*)(out + (size_t)m * OC + nn) = o;
            }
        }
    }
}

// ---------------- launch ----------------
extern "C" void kernel_launch(void* const* d_in, const int* in_sizes, int n_in,
                              void* d_out, int out_size, void* d_ws, size_t ws_size,
                              hipStream_t stream) {
    const float* x  = (const float*)d_in[0];
    const float* W  = (const float*)d_in[1];
    const float* b  = (const float*)d_in[2];
    const int*   ei = (const int*)d_in[3];
    const float* ew = (const float*)d_in[4];
    const int* row = ei;            // source
    const int* col = ei + NE;       // target
    float* out = (float*)d_out;

    char* w0 = (char*)d_ws;
    unsigned long long* deg64 = (unsigned long long*)w0;  w0 += NPAD * 8;
    float* dinv  = (float*)w0;                   w0 += NPAD * 4;
    int*   sp    = (int*)w0;                     w0 += NPAD * 4;
    int*   bsum  = (int*)w0;                     w0 += 256 * 4;
    int*   eord  = (int*)w0;                     w0 += NE * 4;
    int2*  epack = (int2*)w0;                    w0 += NE * 8;
    unsigned short* WT = (unsigned short*)w0;    w0 += IC * OC * 2;
    unsigned short* xb = (unsigned short*)w0;    // NN*IC bf16 = 12.8 MB

    k_init      <<<NB, 256, 0, stream>>>(deg64);
    k_pass1     <<<NEB4, 256, 0, stream>>>(col, ew, deg64, eord, x, xb, W, WT);
    k_dinv_scan <<<NB, 256, 0, stream>>>(deg64, dinv, sp, bsum);
    k_scan2     <<<1, 256, 0, stream>>>(bsum);
    k_fill      <<<NEB4, 256, 0, stream>>>(row, col, ew, dinv, sp, bsum, eord, epack);
    k_gathergemm<<<(NN + 63) / 64, 256, 0, stream>>>(xb, sp, bsum, epack, dinv, WT, b, out);
}

// Round 7
// 178.029 us; speedup vs baseline: 1.2802x; 1.2802x over previous
//
#include <hip/hip_runtime.h>
#include <hip/hip_bf16.h>
#include <math.h>

#define NN 50000
#define NE 500000
#define IC 128
#define OC 256
#define NPAD 50176            // 196 * 256
#define NB 196                // scan blocks
#define NEB4 489              // ceil(NE/1024) edge blocks, 4 edges/thread
#define CONVSTRIDE (NEB4 * 256)

typedef short bf16x8 __attribute__((ext_vector_type(8)));
typedef float f32x4 __attribute__((ext_vector_type(4)));

static __device__ inline unsigned short f2b(float f) {
    __hip_bfloat16 h = __float2bfloat16(f);   // RNE
    return *reinterpret_cast<unsigned short*>(&h);
}
static __device__ inline float b2f(short u) {
    unsigned v = ((unsigned)(unsigned short)u) << 16;
    return __int_as_float(v);
}

// ---------------- init: deg64 = (count=0, degfix = 1.0 in 8.24) ----------------
__global__ void k_init(unsigned long long* __restrict__ deg64) {
    int i = blockIdx.x * 256 + threadIdx.x;   // i < NPAD
    deg64[i] = (unsigned long long)(1u << 24);   // self-loop weight 1
}

// ---------------- pass1: 4 edges/thread, 4 independent u64 atomics in flight;
//                  fused x->bf16 and W->WT conversions ----------------
__global__ __launch_bounds__(256) void k_pass1(const int* __restrict__ col,
                        const float* __restrict__ ew,
                        unsigned long long* __restrict__ deg64,
                        int* __restrict__ eord,
                        const float* __restrict__ x,
                        unsigned short* __restrict__ xb,
                        const float* __restrict__ W,
                        unsigned short* __restrict__ WT) {
    const int base = blockIdx.x * 1024 + threadIdx.x;
    int   cs[4];
    float ws[4];
    #pragma unroll
    for (int j = 0; j < 4; ++j) {
        int e = base + j * 256;
        if (e < NE) { cs[j] = col[e]; ws[j] = ew[e]; }
    }
    unsigned long long olds[4];
    #pragma unroll
    for (int j = 0; j < 4; ++j) {
        int e = base + j * 256;
        if (e < NE) {
            float w = 1.0f / (1.0f + expf(-ws[j]));
            unsigned long long pack = (1ull << 32) | (unsigned long long)(unsigned)(w * 16777216.0f);
            olds[j] = atomicAdd(&deg64[cs[j]], pack);
        }
    }
    #pragma unroll
    for (int j = 0; j < 4; ++j) {
        int e = base + j * 256;
        if (e < NE) eord[e] = (int)(olds[j] >> 32);
    }
    // fused x -> bf16 (grid-stride over float4 units)
    const int g = blockIdx.x * 256 + threadIdx.x;
    const int NX = NN * (IC / 4);
    for (int i = g; i < NX; i += CONVSTRIDE) {
        float4 v = ((const float4*)x)[i];
        ushort4 o;
        o.x = f2b(v.x); o.y = f2b(v.y); o.z = f2b(v.z); o.w = f2b(v.w);
        ((ushort4*)xb)[i] = o;
    }
    // fused W -> W^T bf16
    if (g < IC * OC) {
        int k = g >> 8;
        int n = g & 255;
        WT[n * IC + k] = f2b(W[g]);
    }
}

// ---------------- dinv + block-scan (fused, same grid) ----------------
__global__ void k_dinv_scan(const unsigned long long* __restrict__ deg64,
                            float* __restrict__ dinv,
                            int* __restrict__ sp,
                            int* __restrict__ bsum) {
    __shared__ int s[256];
    int t = threadIdx.x;
    int i = blockIdx.x * 256 + t;
    unsigned long long v = deg64[i];
    int cnt = (int)(v >> 32);
    float deg = (float)(unsigned)v * (1.0f / 16777216.0f);
    dinv[i] = rsqrtf(deg);                    // deg >= 1 always
    s[t] = cnt;
    __syncthreads();
    #pragma unroll
    for (int off = 1; off < 256; off <<= 1) {
        int add = (t >= off) ? s[t - off] : 0;
        __syncthreads();
        s[t] += add;
        __syncthreads();
    }
    sp[i] = s[t] - cnt;                       // exclusive within block
    if (t == 255) bsum[blockIdx.x] = s[255];
}

__global__ void k_scan2(int* __restrict__ bsum) {
    __shared__ int s[256];
    int t = threadIdx.x;
    int v = (t < NB) ? bsum[t] : 0;
    s[t] = v;
    __syncthreads();
    #pragma unroll
    for (int off = 1; off < 256; off <<= 1) {
        int add = (t >= off) ? s[t - off] : 0;
        __syncthreads();
        s[t] += add;
        __syncthreads();
    }
    if (t < NB) bsum[t] = s[t] - v;           // exclusive block offsets
}

// ---------------- fill: no atomic, 4 edges/thread ----------------
__global__ __launch_bounds__(256) void k_fill(const int* __restrict__ row,
                       const int* __restrict__ col,
                       const float* __restrict__ ew,
                       const float* __restrict__ dinv,
                       const int* __restrict__ sp,
                       const int* __restrict__ bsum,
                       const int* __restrict__ eord,
                       int2* __restrict__ epack) {
    const int base = blockIdx.x * 1024 + threadIdx.x;
    #pragma unroll
    for (int j = 0; j < 4; ++j) {
        int e = base + j * 256;
        if (e < NE) {
            int r = row[e], t = col[e];
            float w = 1.0f / (1.0f + expf(-ew[e]));
            float nrm = dinv[r] * w * dinv[t];
            int pos = sp[t] + bsum[t >> 8] + eord[e];
            int2 p;
            p.x = r;
            p.y = __float_as_int(nrm);
            epack[pos] = p;
        }
    }
}

// ---------------- gather (bf16): aggb[n] = bf16( xb[n]*dinv^2 + sum_e xb[r]*nrm ) ----------------
// 16 nodes per block, 16 lanes per node, bf16x8 (16B) per lane; 4 load chains in flight
__global__ __launch_bounds__(256) void k_gather(const unsigned short* __restrict__ xb,
                                                const int* __restrict__ sp,
                                                const int* __restrict__ bsum,
                                                const int2* __restrict__ epack,
                                                const float* __restrict__ dinv,
                                                unsigned short* __restrict__ aggb) {
    int n = blockIdx.x * 16 + (threadIdx.x >> 4);
    if (n >= NN) return;
    int lane = threadIdx.x & 15;
    const bf16x8* xv = (const bf16x8*)xb;     // row = 16 units of 8 bf16

    float di = dinv[n];
    float s2 = di * di;
    bf16x8 xs = xv[(size_t)n * 16 + lane];
    float acc[8];
    #pragma unroll
    for (int c = 0; c < 8; ++c) acc[c] = b2f(xs[c]) * s2;

    int s = sp[n] + bsum[n >> 8];
    int t = sp[n + 1] + bsum[(n + 1) >> 8];
    int e = s;
    for (; e + 4 <= t; e += 4) {              // 4 independent load chains
        int2 p0 = epack[e];
        int2 p1 = epack[e + 1];
        int2 p2 = epack[e + 2];
        int2 p3 = epack[e + 3];
        bf16x8 v0 = xv[(size_t)p0.x * 16 + lane];
        bf16x8 v1 = xv[(size_t)p1.x * 16 + lane];
        bf16x8 v2 = xv[(size_t)p2.x * 16 + lane];
        bf16x8 v3 = xv[(size_t)p3.x * 16 + lane];
        float w0 = __int_as_float(p0.y);
        float w1 = __int_as_float(p1.y);
        float w2 = __int_as_float(p2.y);
        float w3 = __int_as_float(p3.y);
        #pragma unroll
        for (int c = 0; c < 8; ++c) acc[c] += b2f(v0[c]) * w0;
        #pragma unroll
        for (int c = 0; c < 8; ++c) acc[c] += b2f(v1[c]) * w1;
        #pragma unroll
        for (int c = 0; c < 8; ++c) acc[c] += b2f(v2[c]) * w2;
        #pragma unroll
        for (int c = 0; c < 8; ++c) acc[c] += b2f(v3[c]) * w3;
    }
    for (; e < t; ++e) {
        int2 p = epack[e];
        bf16x8 v = xv[(size_t)p.x * 16 + lane];
        float w = __int_as_float(p.y);
        #pragma unroll
        for (int c = 0; c < 8; ++c) acc[c] += b2f(v[c]) * w;
    }

    bf16x8 o;
    #pragma unroll
    for (int c = 0; c < 8; ++c) o[c] = (short)f2b(acc[c]);
    ((bf16x8*)aggb)[(size_t)n * 16 + lane] = o;
}

// ---------------- GEMM: out = aggb @ WT^T + b  (MFMA, no LDS, swapped operands) ----------------
// block 256 = 4 waves; block tile 64m x 128n; wave tile 32m x 64n; grid (2, 782)
__global__ __launch_bounds__(256) void k_gemm(const unsigned short* __restrict__ agg,
                                              const unsigned short* __restrict__ WT,
                                              const float* __restrict__ bias,
                                              float* __restrict__ out) {
    const int w = threadIdx.x >> 6;
    const int lane = threadIdx.x & 63;
    const int m0 = blockIdx.y * 64 + (w >> 1) * 32;
    const int n0 = blockIdx.x * 128 + (w & 1) * 64;
    const int lm = lane & 15;
    const int lk = (lane >> 4) * 8;

    f32x4 acc[2][4] = {};
    #pragma unroll
    for (int ks = 0; ks < 4; ++ks) {
        const int k0 = ks * 32 + lk;
        bf16x8 wf[4], af[2];
        #pragma unroll
        for (int j = 0; j < 4; ++j)
            wf[j] = *(const bf16x8*)(WT + (size_t)(n0 + j * 16 + lm) * IC + k0);
        #pragma unroll
        for (int i = 0; i < 2; ++i)
            af[i] = *(const bf16x8*)(agg + (size_t)(m0 + i * 16 + lm) * IC + k0);
        #pragma unroll
        for (int i = 0; i < 2; ++i)
            #pragma unroll
            for (int j = 0; j < 4; ++j)
                acc[i][j] = __builtin_amdgcn_mfma_f32_16x16x32_bf16(wf[j], af[i], acc[i][j], 0, 0, 0);
    }

    // swapped D layout: col(lane&15) = m-dim, row((lane>>4)*4+reg) = n-dim -> float4 along n
    const int mcol = lane & 15;
    const int nb4 = (lane >> 4) * 4;
    #pragma unroll
    for (int i = 0; i < 2; ++i) {
        int m = m0 + i * 16 + mcol;
        if (m < NN) {
            #pragma unroll
            for (int j = 0; j < 4; ++j) {
                int nn = n0 + j * 16 + nb4;
                float4 bv = *(const float4*)&bias[nn];
                float4 o;
                o.x = acc[i][j][0] + bv.x;
                o.y = acc[i][j][1] + bv.y;
                o.z = acc[i][j][2] + bv.z;
                o.w = acc[i][j][3] + bv.w;
                *(float4*)(out + (size_t)m * OC + nn) = o;
            }
        }
    }
}

// ---------------- launch ----------------
extern "C" void kernel_launch(void* const* d_in, const int* in_sizes, int n_in,
                              void* d_out, int out_size, void* d_ws, size_t ws_size,
                              hipStream_t stream) {
    const float* x  = (const float*)d_in[0];
    const float* W  = (const float*)d_in[1];
    const float* b  = (const float*)d_in[2];
    const int*   ei = (const int*)d_in[3];
    const float* ew = (const float*)d_in[4];
    const int* row = ei;            // source
    const int* col = ei + NE;       // target
    float* out = (float*)d_out;

    char* w0 = (char*)d_ws;
    unsigned long long* deg64 = (unsigned long long*)w0;  w0 += NPAD * 8;
    float* dinv  = (float*)w0;                   w0 += NPAD * 4;
    int*   sp    = (int*)w0;                     w0 += NPAD * 4;
    int*   bsum  = (int*)w0;                     w0 += 256 * 4;
    int*   eord  = (int*)w0;                     w0 += NE * 4;
    int2*  epack = (int2*)w0;                    w0 += NE * 8;
    unsigned short* WT   = (unsigned short*)w0;  w0 += IC * OC * 2;
    unsigned short* xb   = (unsigned short*)w0;  w0 += (size_t)NN * IC * 2;
    unsigned short* aggb = (unsigned short*)w0;  // NPAD*IC bf16 = 12.8 MB

    k_init      <<<NB, 256, 0, stream>>>(deg64);
    k_pass1     <<<NEB4, 256, 0, stream>>>(col, ew, deg64, eord, x, xb, W, WT);
    k_dinv_scan <<<NB, 256, 0, stream>>>(deg64, dinv, sp, bsum);
    k_scan2     <<<1, 256, 0, stream>>>(bsum);
    k_fill      <<<NEB4, 256, 0, stream>>>(row, col, ew, dinv, sp, bsum, eord, epack);
    k_gather    <<<(NN + 15) / 16, 256, 0, stream>>>(xb, sp, bsum, epack, dinv, aggb);
    k_gemm      <<<dim3(2, (NN + 63) / 64), 256, 0, stream>>>(aggb, WT, b, out);
}